// Round 20
// baseline (536.183 us; speedup 1.0000x reference)
//
#include <hip/hip_runtime.h>
#include <hip/hip_fp16.h>
#include <math.h>

#define NTOK 16384
#define KCB  4096
#define DIM  128
#define NG8  (KCB / 8)      // 512 8-code groups
#define RPBLOCKS (1024 + NTOK / 4)   // resolve_pair grid size

typedef short bf16x8 __attribute__((ext_vector_type(8)));
typedef float f32x4  __attribute__((ext_vector_type(4)));

// RNE float -> bf16 bits
static __device__ inline unsigned short rne_bf16(float f) {
  unsigned u = __float_as_uint(f);
  return (unsigned short)((u + 0x7FFFu + ((u >> 16) & 1u)) >> 16);
}

// ---------------------------------------------------------------------------
// ws layout (float offsets from W):
//   [0]          sumx2[NTOK]
//   +NTOK        sumc2[KCB]
//   +KCB         absum[NTOK]
//   +NTOK        cnt[KCB] (int)
//   +KCB         msum[NTOK]
//   +NTOK        csum[NTOK]
//   +NTOK        pairsum[4096]
//   +4096        pairmin[4096]
//   +4096        done (unsigned) + pad to 16 floats
//   +16          cbh[KCB*DIM] (ushort bf16 hi)
//   +KCB*DIM/2   gmax8[NTOK*NG8] (ushort fp16, row-major per token)
// ---------------------------------------------------------------------------

// Fused: rownorm (+cnt zero, +done zero) blocks [0,5120); convert [5120,5376).
__global__ __launch_bounds__(256) void k_prep(const float* __restrict__ lat,
                                              const float* __restrict__ cb,
                                              float* __restrict__ sumx2,
                                              float* __restrict__ sumc2,
                                              float* __restrict__ absum,
                                              int* __restrict__ cnt,
                                              unsigned* __restrict__ done,
                                              unsigned short* __restrict__ cbh) {
  if (blockIdx.x < (NTOK + KCB) / 4) {
    if (blockIdx.x == 0 && threadIdx.x == 0) *done = 0u;
    if (blockIdx.x < 16) cnt[blockIdx.x * 256 + threadIdx.x] = 0;
    const int row  = blockIdx.x * 4 + (threadIdx.x >> 6);
    const int lane = threadIdx.x & 63;
    const float* src = (row < NTOK) ? (lat + (size_t)row * DIM)
                                    : (cb + (size_t)(row - NTOK) * DIM);
    float2 v = *(const float2*)(src + lane * 2);
    double s  = (double)v.x * (double)v.x + (double)v.y * (double)v.y;
    double sa = fabs((double)v.x) + fabs((double)v.y);
#pragma unroll
    for (int m = 32; m >= 1; m >>= 1) {
      s  += __shfl_xor(s, m, 64);
      sa += __shfl_xor(sa, m, 64);
    }
    if (lane == 0) {
      if (row < NTOK) { sumx2[row] = (float)s; absum[row] = (float)sa; }
      else            sumc2[row - NTOK] = (float)s;
    }
  } else {
    const int b = blockIdx.x - (NTOK + KCB) / 4;
    const int base = (b * 256 + threadIdx.x) * 8;
    float4 v0 = *(const float4*)(cb + base);
    float4 v1 = *(const float4*)(cb + base + 4);
    ushort4 o0, o1;
    o0.x = rne_bf16(v0.x); o0.y = rne_bf16(v0.y); o0.z = rne_bf16(v0.z); o0.w = rne_bf16(v0.w);
    o1.x = rne_bf16(v1.x); o1.y = rne_bf16(v1.y); o1.z = rne_bf16(v1.z); o1.w = rne_bf16(v1.w);
    *(ushort4*)(cbh + base) = o0;
    *(ushort4*)(cbh + base + 4) = o1;
  }
}

// bf16 MFMA scan. Same per-(ct,rt) math as R14-R19 (gmax8 bit-identical);
// grid y 16->32 (2 ct-tiles/block) shrinks gbuf to 10.2 KB -> LDS 26.6 KB
// -> 6 blocks/CU (was 4): more waves to hide the barrier+MFMA latency.
__global__ __launch_bounds__(256) void k_approx(const float* __restrict__ lat,
                                                const unsigned short* __restrict__ cbh,
                                                unsigned short* __restrict__ gmax8) {
  __shared__ __align__(16) unsigned char smem[16384];
  __shared__ __align__(16) unsigned short gbuf[256][20];  // 16 g8 + pad
  const int t = threadIdx.x;
  const int w = t >> 6, l = t & 63;
  const int l15 = l & 15, lq = l >> 4;
  const int tokb = blockIdx.x * 256 + w * 64;
  const int ct0 = blockIdx.y * 2;

  bf16x8 bfr[4][4];
#pragma unroll
  for (int ctile = 0; ctile < 4; ++ctile) {
    const float* row = lat + (size_t)(tokb + ctile * 16 + l15) * DIM;
#pragma unroll
    for (int ks = 0; ks < 4; ++ks) {
      const int d0 = ks * 32 + lq * 4;
      float4 c0 = *(const float4*)(row + d0);
      float4 c1 = *(const float4*)(row + d0 + 16);
      union { ushort4 u4[2]; bf16x8 v; } cv;
      cv.u4[0].x = rne_bf16(c0.x); cv.u4[0].y = rne_bf16(c0.y);
      cv.u4[0].z = rne_bf16(c0.z); cv.u4[0].w = rne_bf16(c0.w);
      cv.u4[1].x = rne_bf16(c1.x); cv.u4[1].y = rne_bf16(c1.y);
      cv.u4[1].z = rne_bf16(c1.z); cv.u4[1].w = rne_bf16(c1.w);
      bfr[ctile][ks] = cv.v;
    }
  }

  for (int it = 0; it < 2; ++it) {
    const int ct = ct0 + it;
    __syncthreads();
    {
      const int r = t & 63, seg = t >> 6;
      const unsigned short* src = cbh + (size_t)(ct * 64 + r) * DIM + seg * 32;
      const int sw = (r & 7) << 4;
#pragma unroll
      for (int i = 0; i < 4; ++i) {
        uint4 v = *(const uint4*)(src + i * 8);
        *(uint4*)(smem + r * 256 + ((seg * 64 + i * 16) ^ sw)) = v;
      }
    }
    __syncthreads();

#pragma unroll
    for (int rt = 0; rt < 4; ++rt) {
      const int row = rt * 16 + l15;
      const int sw = (row & 7) << 4;
      bf16x8 afr[4];
#pragma unroll
      for (int ks = 0; ks < 4; ++ks) {
        const int off = ks * 64 + lq * 8;
        union { uint2 u2[2]; bf16x8 v; } cv;
        cv.u2[0] = *(const uint2*)(smem + row * 256 + (off ^ sw));
        cv.u2[1] = *(const uint2*)(smem + row * 256 + (((off + 32)) ^ sw));
        afr[ks] = cv.v;
      }
      f32x4 acc[4];
#pragma unroll
      for (int c = 0; c < 4; ++c) acc[c] = (f32x4){0.0f, 0.0f, 0.0f, 0.0f};
#pragma unroll
      for (int ks = 0; ks < 4; ++ks)
#pragma unroll
        for (int c = 0; c < 4; ++c)
          acc[c] = __builtin_amdgcn_mfma_f32_16x16x32_bf16(afr[ks], bfr[c][ks], acc[c], 0, 0, 0);
#pragma unroll
      for (int c = 0; c < 4; ++c) {
        float gm = fmaxf(fmaxf(acc[c][0], acc[c][1]), fmaxf(acc[c][2], acc[c][3]));
        gm = fmaxf(gm, __shfl_xor(gm, 16, 64));
        if ((lq & 1) == 0) {
          const int tokl = w * 64 + c * 16 + l15;
          gbuf[tokl][it * 8 + rt * 2 + (lq >> 1)] =
              __half_as_ushort(__float2half(gm));
        }
      }
    }
  }

  __syncthreads();
  // writeback: 16 g8 values per token (2 uint4), coalesced
  for (int c = t; c < 512; c += 256) {
    const int token = c >> 1, seg = c & 1;
    uint2 a = *(const uint2*)(&gbuf[token][seg * 8]);
    uint2 b = *(const uint2*)(&gbuf[token][seg * 8 + 4]);
    uint4 o = make_uint4(a.x, a.y, b.x, b.y);
    *(uint4*)(gmax8 + (size_t)(blockIdx.x * 256 + token) * NG8 +
              blockIdx.y * 16 + seg * 8) = o;
  }
}

// Fused PAIR [0,1024) + RESOLVE [1024,5120) — R19 exact — plus last-block
// final reduction (counter + threadfence; deterministic fixed-order tree).
__global__ __launch_bounds__(256) void k_resolve_pair(
    const float* __restrict__ lat,
    const float* __restrict__ cb,
    const float* __restrict__ sumx2,
    const float* __restrict__ sumc2,
    const float* __restrict__ absum,
    const unsigned short* __restrict__ gmax8,
    const unsigned short* __restrict__ cbh,
    float* __restrict__ qout,
    float* __restrict__ idx_out,
    float* __restrict__ msum,
    float* __restrict__ csum,
    int* __restrict__ cnt,
    float* __restrict__ pairsum,
    float* __restrict__ pairmin,
    unsigned* __restrict__ done,
    float* __restrict__ outs) {
  __shared__ __align__(16) unsigned char pool[16640];
  __shared__ unsigned lastf;

  if (blockIdx.x < 1024) {
    // ---------------- PAIR path ----------------
    const int f = blockIdx.x;
    const int bx = f & 15, by = f >> 4;
    unsigned char* smem = pool;
    float* qs = (float*)(pool + 16384);
    const int t = threadIdx.x;
    const int w = t >> 6, l = t & 63;
    const int l15 = l & 15, lq = l >> 4;
    const int jb = bx * 256 + w * 64;
    const int kb = by * 64;

    {
      const int r = t & 63, seg = t >> 6;
      const unsigned short* src = cbh + (size_t)(kb + r) * DIM + seg * 32;
      const int sw = (r & 7) << 4;
#pragma unroll
      for (int i = 0; i < 4; ++i) {
        uint4 v = *(const uint4*)(src + i * 8);
        *(uint4*)(smem + r * 256 + ((seg * 64 + i * 16) ^ sw)) = v;
      }
      if (t < 64) qs[t] = sumc2[kb + t];
    }

    bf16x8 bfr[4][4];
    float qj[4];
#pragma unroll
    for (int ct = 0; ct < 4; ++ct) {
      const unsigned short* rh = cbh + (size_t)(jb + ct * 16 + l15) * DIM;
#pragma unroll
      for (int ks = 0; ks < 4; ++ks) {
        const int d0 = ks * 32 + lq * 4;
        union { ushort4 u4[2]; bf16x8 v; } cvv;
        cvv.u4[0] = *(const ushort4*)(rh + d0);
        cvv.u4[1] = *(const ushort4*)(rh + d0 + 16);
        bfr[ct][ks] = cvv.v;
      }
      qj[ct] = sumc2[jb + ct * 16 + l15];
    }
    __syncthreads();

    float lsum = 0.0f, lmin = INFINITY;

#pragma unroll
    for (int rt = 0; rt < 4; ++rt) {
      const int row = rt * 16 + l15;
      const int sw = (row & 7) << 4;
      bf16x8 afr[4];
#pragma unroll
      for (int ks = 0; ks < 4; ++ks) {
        const int off = ks * 64 + lq * 8;
        union { uint2 u2[2]; bf16x8 v; } cv;
        cv.u2[0] = *(const uint2*)(smem + row * 256 + (off ^ sw));
        cv.u2[1] = *(const uint2*)(smem + row * 256 + (((off + 32)) ^ sw));
        afr[ks] = cv.v;
      }
      f32x4 acc[4];
#pragma unroll
      for (int c = 0; c < 4; ++c) acc[c] = (f32x4){0.0f, 0.0f, 0.0f, 0.0f};
#pragma unroll
      for (int ks = 0; ks < 4; ++ks)
#pragma unroll
        for (int c = 0; c < 4; ++c)
          acc[c] = __builtin_amdgcn_mfma_f32_16x16x32_bf16(afr[ks], bfr[c][ks], acc[c], 0, 0, 0);

#pragma unroll
      for (int c = 0; c < 4; ++c) {
        const int jg = jb + c * 16 + l15;
#pragma unroll
        for (int reg = 0; reg < 4; ++reg) {
          const int krl = rt * 16 + lq * 4 + reg;
          const int kg = kb + krl;
          const float d2 = (qj[c] + qs[krl]) - 2.0f * acc[c][reg];
          const float dd = sqrtf(fmaxf(d2, 0.0f));
          lsum += dd;
          if (jg != kg) lmin = fminf(lmin, dd);
        }
      }
    }

#pragma unroll
    for (int s = 32; s >= 1; s >>= 1) {
      lsum += __shfl_xor(lsum, s, 64);
      lmin = fminf(lmin, __shfl_xor(lmin, s, 64));
    }
    if (l == 0) {
      const int slot = f * 4 + w;
      pairsum[slot] = lsum;
      pairmin[slot] = lmin;
    }
  } else {
    // ---------------- RESOLVE path (R19 exact) ----------------
    const int bid = blockIdx.x - 1024;
    float (*xs)[DIM] = (float (*)[DIM])pool;
    unsigned short (*q)[NG8] = (unsigned short (*)[NG8])(pool + 2048);
    const int w = threadIdx.x >> 6, l = threadIdx.x & 63;
    const int tok = bid * 4 + w;

    const float2 xv = *(const float2*)(lat + (size_t)tok * DIM + l * 2);
    const uint4 hv = *(const uint4*)(gmax8 + (size_t)tok * NG8 + l * 8);
    const float sx = sumx2[tok];
    const float ab = absum[tok];
    *(float2*)(&xs[w][l * 2]) = xv;

    float hf[8];
    hf[0] = __half2float(__ushort_as_half((unsigned short)(hv.x & 0xFFFFu)));
    hf[1] = __half2float(__ushort_as_half((unsigned short)(hv.x >> 16)));
    hf[2] = __half2float(__ushort_as_half((unsigned short)(hv.y & 0xFFFFu)));
    hf[3] = __half2float(__ushort_as_half((unsigned short)(hv.y >> 16)));
    hf[4] = __half2float(__ushort_as_half((unsigned short)(hv.z & 0xFFFFu)));
    hf[5] = __half2float(__ushort_as_half((unsigned short)(hv.z >> 16)));
    hf[6] = __half2float(__ushort_as_half((unsigned short)(hv.w & 0xFFFFu)));
    hf[7] = __half2float(__ushort_as_half((unsigned short)(hv.w >> 16)));
    float m = hf[0];
#pragma unroll
    for (int i = 1; i < 8; ++i) m = fmaxf(m, hf[i]);
#pragma unroll
    for (int s = 32; s >= 1; s >>= 1) m = fmaxf(m, __shfl_xor(m, s, 64));
    const float thr = m - (ab * 2.0e-6f + 7.0e-5f);

    const unsigned long long ltm = (1ull << l) - 1ull;
    int n = 0;
#pragma unroll
    for (int i = 0; i < 8; ++i) {
      const bool f2 = (hf[i] >= thr);
      const unsigned long long b = __ballot(f2);
      if (f2) q[w][n + __popcll(b & ltm)] = (unsigned short)(l * 8 + i);
      n += __popcll(b);
    }

    const int slot = l >> 3, cidx = l & 7;
    unsigned long long bestp = ~0ull;
    const float4* xr4 = (const float4*)xs[w];

    for (int base = 0; base < n; base += 8) {
      unsigned long long pack = ~0ull;
      const int qi = base + slot;
      if (qi < n) {
        const int g = (int)q[w][qi];
        const int code = g * 8 + cidx;
        const float4* crow = (const float4*)(cb + (size_t)code * DIM);
        float acc = 0.0f;
#pragma unroll 8
        for (int ch = 0; ch < 32; ++ch) {
          const float4 c = crow[ch];
          const float4 x = xr4[ch];
          acc = fmaf(x.x, c.x, acc); acc = fmaf(x.y, c.y, acc);
          acc = fmaf(x.z, c.z, acc); acc = fmaf(x.w, c.w, acc);
        }
        const float dist = (sx - 2.0f * acc) + sumc2[code];
        pack = ((unsigned long long)__float_as_uint(dist) << 32) | (unsigned)code;
      }
#pragma unroll
      for (int s = 32; s >= 1; s >>= 1) {
        const unsigned long long o = __shfl_xor(pack, s, 64);
        pack = (o < pack) ? o : pack;
      }
      bestp = (pack < bestp) ? pack : bestp;
    }

    const int code = (int)(bestp & 0xFFFFFFFFull);
    const float2 c2 = *(const float2*)(cb + (size_t)code * DIM + l * 2);
    const float o0 = xv.x + (c2.x - xv.x);
    const float o1 = xv.y + (c2.y - xv.y);
    *(float2*)(qout + (size_t)tok * DIM + l * 2) = make_float2(o0, o1);
    const float e0 = xv.x - c2.x, e1 = xv.y - c2.y;
    float msel = e0 * e0 + e1 * e1;
    float dt = xv.x * c2.x + xv.y * c2.y;
#pragma unroll
    for (int s = 32; s >= 1; s >>= 1) {
      msel += __shfl_xor(msel, s, 64);
      dt += __shfl_xor(dt, s, 64);
    }
    if (l == 0) {
      const float nx = fmaxf(sqrtf(sx), 1e-12f);
      const float nc = fmaxf(sqrtf(sumc2[code]), 1e-12f);
      msum[tok] = msel;
      csum[tok] = dt / (nx * nc);
      idx_out[tok] = (float)code;
      atomicAdd(&cnt[code], 1);
    }
  }

  // ---------------- last-block final ----------------
  __syncthreads();
  __threadfence();
  if (threadIdx.x == 0)
    lastf = (atomicAdd(done, 1u) == (unsigned)(RPBLOCKS - 1)) ? 1u : 0u;
  __syncthreads();
  if (lastf) {
    __threadfence();
    const int t = threadIdx.x;
    float* sh  = (float*)pool;          // 4 x 256 floats = 4 KB
    float* sh2 = sh + 256;
    float* sh3 = sh + 512;
    float* sh4 = sh + 768;
    float ent = 0.0f;
    for (int k = t; k < KCB; k += 256) {
      const float p = (float)cnt[k] * (1.0f / (float)NTOK);
      ent += p * logf(p + 1e-10f);
    }
    float ms = 0.0f, cs = 0.0f;
    for (int i = t; i < NTOK; i += 256) { ms += msum[i]; cs += csum[i]; }
    float ps = 0.0f, pm = INFINITY;
    for (int i = t; i < 4096; i += 256) { ps += pairsum[i]; pm = fminf(pm, pairmin[i]); }

    sh[t] = ent; sh2[t] = ms; sh3[t] = cs; sh4[t] = ps;
    __syncthreads();
    for (int s = 128; s >= 1; s >>= 1) {
      if (t < s) { sh[t] += sh[t + s]; sh2[t] += sh2[t + s];
                   sh3[t] += sh3[t + s]; sh4[t] += sh4[t + s]; }
      __syncthreads();
    }
    const float ent_tot = sh[0];
    const float ms_tot  = sh2[0];
    const float cs_tot  = sh3[0];
    const float ps_tot  = sh4[0];
    __syncthreads();
    sh[t] = pm;
    __syncthreads();
    for (int s = 128; s >= 1; s >>= 1) {
      if (t < s) sh[t] = fminf(sh[t], sh[t + s]);
      __syncthreads();
    }
    if (t == 0) {
      const float mse = ms_tot * (1.0f / (float)(NTOK * DIM));
      outs[0] = 0.25f * mse;
      outs[1] = mse;
      outs[2] = expf(-ent_tot);
      outs[3] = cs_tot * (1.0f / (float)NTOK);
      outs[4] = ps_tot / ((float)KCB * (float)(KCB - 1));
      outs[5] = sh[0];
    }
  }
}

extern "C" void kernel_launch(void* const* d_in, const int* in_sizes, int n_in,
                              void* d_out, int out_size, void* d_ws, size_t ws_size,
                              hipStream_t stream) {
  const float* lat = (const float*)d_in[0];
  const float* cb  = (const float*)d_in[1];

  float* out     = (float*)d_out;
  float* qout    = out;
  float* idx_out = out + (size_t)NTOK * DIM;
  float* outs    = idx_out + NTOK;

  float* W        = (float*)d_ws;
  float* sumx2    = W;                             // NTOK
  float* sumc2    = sumx2 + NTOK;                  // KCB
  float* absum    = sumc2 + KCB;                   // NTOK
  int*   cnt      = (int*)(absum + NTOK);          // KCB
  float* msum     = (float*)(cnt + KCB);           // NTOK
  float* csum     = msum + NTOK;                   // NTOK
  float* pairsum  = csum + NTOK;                   // 4096
  float* pairmin  = pairsum + 4096;                // 4096
  unsigned* done  = (unsigned*)(pairmin + 4096);   // 1 (+15 pad)
  unsigned short* cbh   = (unsigned short*)(pairmin + 4096 + 16);  // KCB*DIM
  unsigned short* gmax8 = cbh + (size_t)KCB * DIM;                 // NTOK*NG8

  hipLaunchKernelGGL(k_prep, dim3((NTOK + KCB) / 4 + KCB * DIM / (256 * 8)),
                     dim3(256), 0, stream, lat, cb, sumx2, sumc2, absum, cnt,
                     done, cbh);
  hipLaunchKernelGGL(k_approx, dim3(NTOK / 256, 32), dim3(256), 0, stream,
                     lat, cbh, gmax8);
  hipLaunchKernelGGL(k_resolve_pair, dim3(RPBLOCKS), dim3(256), 0, stream,
                     lat, cb, sumx2, sumc2, absum, gmax8, cbh,
                     qout, idx_out, msum, csum, cnt, pairsum, pairmin,
                     done, outs);
}

// Round 21
// 123.682 us; speedup vs baseline: 4.3352x; 4.3352x over previous
//
#include <hip/hip_runtime.h>
#include <hip/hip_fp16.h>
#include <math.h>

#define NTOK 16384
#define KCB  4096
#define DIM  128
#define NG8  (KCB / 8)      // 512 8-code groups

typedef short bf16x8 __attribute__((ext_vector_type(8)));
typedef float f32x4  __attribute__((ext_vector_type(4)));

// RNE float -> bf16 bits
static __device__ inline unsigned short rne_bf16(float f) {
  unsigned u = __float_as_uint(f);
  return (unsigned short)((u + 0x7FFFu + ((u >> 16) & 1u)) >> 16);
}

// ---------------------------------------------------------------------------
// ws layout (float offsets from W):
//   [0]          sumx2[NTOK]
//   +NTOK        sumc2[KCB]
//   +KCB         absum[NTOK]
//   +NTOK        cnt[KCB] (int)
//   +KCB         msum[NTOK]
//   +NTOK        csum[NTOK]
//   +NTOK        pairsum[4096]
//   +4096        pairmin[4096]
//   +4096        cbh[KCB*DIM] (ushort bf16 hi)
//   +KCB*DIM/2   gmax8[NTOK*NG8] (ushort fp16, row-major per token)
// ---------------------------------------------------------------------------

// Fused: rownorm (+cnt zero) blocks [0, 5120) ; convert blocks [5120, 5376).
__global__ __launch_bounds__(256) void k_prep(const float* __restrict__ lat,
                                              const float* __restrict__ cb,
                                              float* __restrict__ sumx2,
                                              float* __restrict__ sumc2,
                                              float* __restrict__ absum,
                                              int* __restrict__ cnt,
                                              unsigned short* __restrict__ cbh) {
  if (blockIdx.x < (NTOK + KCB) / 4) {
    if (blockIdx.x < 16) cnt[blockIdx.x * 256 + threadIdx.x] = 0;
    const int row  = blockIdx.x * 4 + (threadIdx.x >> 6);
    const int lane = threadIdx.x & 63;
    const float* src = (row < NTOK) ? (lat + (size_t)row * DIM)
                                    : (cb + (size_t)(row - NTOK) * DIM);
    float2 v = *(const float2*)(src + lane * 2);
    double s  = (double)v.x * (double)v.x + (double)v.y * (double)v.y;
    double sa = fabs((double)v.x) + fabs((double)v.y);
#pragma unroll
    for (int m = 32; m >= 1; m >>= 1) {
      s  += __shfl_xor(s, m, 64);
      sa += __shfl_xor(sa, m, 64);
    }
    if (lane == 0) {
      if (row < NTOK) { sumx2[row] = (float)s; absum[row] = (float)sa; }
      else            sumc2[row - NTOK] = (float)s;
    }
  } else {
    const int b = blockIdx.x - (NTOK + KCB) / 4;
    const int base = (b * 256 + threadIdx.x) * 8;
    float4 v0 = *(const float4*)(cb + base);
    float4 v1 = *(const float4*)(cb + base + 4);
    ushort4 o0, o1;
    o0.x = rne_bf16(v0.x); o0.y = rne_bf16(v0.y); o0.z = rne_bf16(v0.z); o0.w = rne_bf16(v0.w);
    o1.x = rne_bf16(v1.x); o1.y = rne_bf16(v1.y); o1.z = rne_bf16(v1.z); o1.w = rne_bf16(v1.w);
    *(ushort4*)(cbh + base) = o0;
    *(ushort4*)(cbh + base + 4) = o1;
  }
}

// bf16 MFMA scan. Same per-(ct,rt) math as R14-R19 (gmax8 bit-identical);
// grid y 16->32 (2 ct-tiles/block): gbuf 10.2 KB -> LDS 26.6 KB -> 6 blk/CU.
__global__ __launch_bounds__(256) void k_approx(const float* __restrict__ lat,
                                                const unsigned short* __restrict__ cbh,
                                                unsigned short* __restrict__ gmax8) {
  __shared__ __align__(16) unsigned char smem[16384];
  __shared__ __align__(16) unsigned short gbuf[256][20];  // 16 g8 + pad
  const int t = threadIdx.x;
  const int w = t >> 6, l = t & 63;
  const int l15 = l & 15, lq = l >> 4;
  const int tokb = blockIdx.x * 256 + w * 64;
  const int ct0 = blockIdx.y * 2;

  bf16x8 bfr[4][4];
#pragma unroll
  for (int ctile = 0; ctile < 4; ++ctile) {
    const float* row = lat + (size_t)(tokb + ctile * 16 + l15) * DIM;
#pragma unroll
    for (int ks = 0; ks < 4; ++ks) {
      const int d0 = ks * 32 + lq * 4;
      float4 c0 = *(const float4*)(row + d0);
      float4 c1 = *(const float4*)(row + d0 + 16);
      union { ushort4 u4[2]; bf16x8 v; } cv;
      cv.u4[0].x = rne_bf16(c0.x); cv.u4[0].y = rne_bf16(c0.y);
      cv.u4[0].z = rne_bf16(c0.z); cv.u4[0].w = rne_bf16(c0.w);
      cv.u4[1].x = rne_bf16(c1.x); cv.u4[1].y = rne_bf16(c1.y);
      cv.u4[1].z = rne_bf16(c1.z); cv.u4[1].w = rne_bf16(c1.w);
      bfr[ctile][ks] = cv.v;
    }
  }

  for (int it = 0; it < 2; ++it) {
    const int ct = ct0 + it;
    __syncthreads();
    {
      const int r = t & 63, seg = t >> 6;
      const unsigned short* src = cbh + (size_t)(ct * 64 + r) * DIM + seg * 32;
      const int sw = (r & 7) << 4;
#pragma unroll
      for (int i = 0; i < 4; ++i) {
        uint4 v = *(const uint4*)(src + i * 8);
        *(uint4*)(smem + r * 256 + ((seg * 64 + i * 16) ^ sw)) = v;
      }
    }
    __syncthreads();

#pragma unroll
    for (int rt = 0; rt < 4; ++rt) {
      const int row = rt * 16 + l15;
      const int sw = (row & 7) << 4;
      bf16x8 afr[4];
#pragma unroll
      for (int ks = 0; ks < 4; ++ks) {
        const int off = ks * 64 + lq * 8;
        union { uint2 u2[2]; bf16x8 v; } cv;
        cv.u2[0] = *(const uint2*)(smem + row * 256 + (off ^ sw));
        cv.u2[1] = *(const uint2*)(smem + row * 256 + (((off + 32)) ^ sw));
        afr[ks] = cv.v;
      }
      f32x4 acc[4];
#pragma unroll
      for (int c = 0; c < 4; ++c) acc[c] = (f32x4){0.0f, 0.0f, 0.0f, 0.0f};
#pragma unroll
      for (int ks = 0; ks < 4; ++ks)
#pragma unroll
        for (int c = 0; c < 4; ++c)
          acc[c] = __builtin_amdgcn_mfma_f32_16x16x32_bf16(afr[ks], bfr[c][ks], acc[c], 0, 0, 0);
#pragma unroll
      for (int c = 0; c < 4; ++c) {
        float gm = fmaxf(fmaxf(acc[c][0], acc[c][1]), fmaxf(acc[c][2], acc[c][3]));
        gm = fmaxf(gm, __shfl_xor(gm, 16, 64));
        if ((lq & 1) == 0) {
          const int tokl = w * 64 + c * 16 + l15;
          gbuf[tokl][it * 8 + rt * 2 + (lq >> 1)] =
              __half_as_ushort(__float2half(gm));
        }
      }
    }
  }

  __syncthreads();
  // writeback: 16 g8 values per token (2 uint4), coalesced
  for (int c = t; c < 512; c += 256) {
    const int token = c >> 1, seg = c & 1;
    uint2 a = *(const uint2*)(&gbuf[token][seg * 8]);
    uint2 b = *(const uint2*)(&gbuf[token][seg * 8 + 4]);
    uint4 o = make_uint4(a.x, a.y, b.x, b.y);
    *(uint4*)(gmax8 + (size_t)(blockIdx.x * 256 + token) * NG8 +
              blockIdx.y * 16 + seg * 8) = o;
  }
}

// Fused PAIR [0,1024) + RESOLVE [1024,5120) — R19 exact.
__global__ __launch_bounds__(256) void k_resolve_pair(
    const float* __restrict__ lat,
    const float* __restrict__ cb,
    const float* __restrict__ sumx2,
    const float* __restrict__ sumc2,
    const float* __restrict__ absum,
    const unsigned short* __restrict__ gmax8,
    const unsigned short* __restrict__ cbh,
    float* __restrict__ qout,
    float* __restrict__ idx_out,
    float* __restrict__ msum,
    float* __restrict__ csum,
    int* __restrict__ cnt,
    float* __restrict__ pairsum,
    float* __restrict__ pairmin) {
  __shared__ __align__(16) unsigned char pool[16640];

  if (blockIdx.x < 1024) {
    // ---------------- PAIR path ----------------
    const int f = blockIdx.x;
    const int bx = f & 15, by = f >> 4;
    unsigned char* smem = pool;
    float* qs = (float*)(pool + 16384);
    const int t = threadIdx.x;
    const int w = t >> 6, l = t & 63;
    const int l15 = l & 15, lq = l >> 4;
    const int jb = bx * 256 + w * 64;
    const int kb = by * 64;

    {
      const int r = t & 63, seg = t >> 6;
      const unsigned short* src = cbh + (size_t)(kb + r) * DIM + seg * 32;
      const int sw = (r & 7) << 4;
#pragma unroll
      for (int i = 0; i < 4; ++i) {
        uint4 v = *(const uint4*)(src + i * 8);
        *(uint4*)(smem + r * 256 + ((seg * 64 + i * 16) ^ sw)) = v;
      }
      if (t < 64) qs[t] = sumc2[kb + t];
    }

    bf16x8 bfr[4][4];
    float qj[4];
#pragma unroll
    for (int ct = 0; ct < 4; ++ct) {
      const unsigned short* rh = cbh + (size_t)(jb + ct * 16 + l15) * DIM;
#pragma unroll
      for (int ks = 0; ks < 4; ++ks) {
        const int d0 = ks * 32 + lq * 4;
        union { ushort4 u4[2]; bf16x8 v; } cvv;
        cvv.u4[0] = *(const ushort4*)(rh + d0);
        cvv.u4[1] = *(const ushort4*)(rh + d0 + 16);
        bfr[ct][ks] = cvv.v;
      }
      qj[ct] = sumc2[jb + ct * 16 + l15];
    }
    __syncthreads();

    float lsum = 0.0f, lmin = INFINITY;

#pragma unroll
    for (int rt = 0; rt < 4; ++rt) {
      const int row = rt * 16 + l15;
      const int sw = (row & 7) << 4;
      bf16x8 afr[4];
#pragma unroll
      for (int ks = 0; ks < 4; ++ks) {
        const int off = ks * 64 + lq * 8;
        union { uint2 u2[2]; bf16x8 v; } cv;
        cv.u2[0] = *(const uint2*)(smem + row * 256 + (off ^ sw));
        cv.u2[1] = *(const uint2*)(smem + row * 256 + (((off + 32)) ^ sw));
        afr[ks] = cv.v;
      }
      f32x4 acc[4];
#pragma unroll
      for (int c = 0; c < 4; ++c) acc[c] = (f32x4){0.0f, 0.0f, 0.0f, 0.0f};
#pragma unroll
      for (int ks = 0; ks < 4; ++ks)
#pragma unroll
        for (int c = 0; c < 4; ++c)
          acc[c] = __builtin_amdgcn_mfma_f32_16x16x32_bf16(afr[ks], bfr[c][ks], acc[c], 0, 0, 0);

#pragma unroll
      for (int c = 0; c < 4; ++c) {
        const int jg = jb + c * 16 + l15;
#pragma unroll
        for (int reg = 0; reg < 4; ++reg) {
          const int krl = rt * 16 + lq * 4 + reg;
          const int kg = kb + krl;
          const float d2 = (qj[c] + qs[krl]) - 2.0f * acc[c][reg];
          const float dd = sqrtf(fmaxf(d2, 0.0f));
          lsum += dd;
          if (jg != kg) lmin = fminf(lmin, dd);
        }
      }
    }

#pragma unroll
    for (int s = 32; s >= 1; s >>= 1) {
      lsum += __shfl_xor(lsum, s, 64);
      lmin = fminf(lmin, __shfl_xor(lmin, s, 64));
    }
    if (l == 0) {
      const int slot = f * 4 + w;
      pairsum[slot] = lsum;
      pairmin[slot] = lmin;
    }
  } else {
    // ---------------- RESOLVE path ----------------
    const int bid = blockIdx.x - 1024;
    float (*xs)[DIM] = (float (*)[DIM])pool;
    unsigned short (*q)[NG8] = (unsigned short (*)[NG8])(pool + 2048);
    const int w = threadIdx.x >> 6, l = threadIdx.x & 63;
    const int tok = bid * 4 + w;

    const float2 xv = *(const float2*)(lat + (size_t)tok * DIM + l * 2);
    const uint4 hv = *(const uint4*)(gmax8 + (size_t)tok * NG8 + l * 8);
    const float sx = sumx2[tok];
    const float ab = absum[tok];
    *(float2*)(&xs[w][l * 2]) = xv;

    float hf[8];
    hf[0] = __half2float(__ushort_as_half((unsigned short)(hv.x & 0xFFFFu)));
    hf[1] = __half2float(__ushort_as_half((unsigned short)(hv.x >> 16)));
    hf[2] = __half2float(__ushort_as_half((unsigned short)(hv.y & 0xFFFFu)));
    hf[3] = __half2float(__ushort_as_half((unsigned short)(hv.y >> 16)));
    hf[4] = __half2float(__ushort_as_half((unsigned short)(hv.z & 0xFFFFu)));
    hf[5] = __half2float(__ushort_as_half((unsigned short)(hv.z >> 16)));
    hf[6] = __half2float(__ushort_as_half((unsigned short)(hv.w & 0xFFFFu)));
    hf[7] = __half2float(__ushort_as_half((unsigned short)(hv.w >> 16)));
    float m = hf[0];
#pragma unroll
    for (int i = 1; i < 8; ++i) m = fmaxf(m, hf[i]);
#pragma unroll
    for (int s = 32; s >= 1; s >>= 1) m = fmaxf(m, __shfl_xor(m, s, 64));
    const float thr = m - (ab * 2.0e-6f + 7.0e-5f);

    const unsigned long long ltm = (1ull << l) - 1ull;
    int n = 0;
#pragma unroll
    for (int i = 0; i < 8; ++i) {
      const bool f2 = (hf[i] >= thr);
      const unsigned long long b = __ballot(f2);
      if (f2) q[w][n + __popcll(b & ltm)] = (unsigned short)(l * 8 + i);
      n += __popcll(b);
    }

    const int slot = l >> 3, cidx = l & 7;
    unsigned long long bestp = ~0ull;
    const float4* xr4 = (const float4*)xs[w];

    for (int base = 0; base < n; base += 8) {
      unsigned long long pack = ~0ull;
      const int qi = base + slot;
      if (qi < n) {
        const int g = (int)q[w][qi];
        const int code = g * 8 + cidx;
        const float4* crow = (const float4*)(cb + (size_t)code * DIM);
        float acc = 0.0f;
#pragma unroll 8
        for (int ch = 0; ch < 32; ++ch) {
          const float4 c = crow[ch];
          const float4 x = xr4[ch];
          acc = fmaf(x.x, c.x, acc); acc = fmaf(x.y, c.y, acc);
          acc = fmaf(x.z, c.z, acc); acc = fmaf(x.w, c.w, acc);
        }
        const float dist = (sx - 2.0f * acc) + sumc2[code];
        pack = ((unsigned long long)__float_as_uint(dist) << 32) | (unsigned)code;
      }
#pragma unroll
      for (int s = 32; s >= 1; s >>= 1) {
        const unsigned long long o = __shfl_xor(pack, s, 64);
        pack = (o < pack) ? o : pack;
      }
      bestp = (pack < bestp) ? pack : bestp;
    }

    const int code = (int)(bestp & 0xFFFFFFFFull);
    const float2 c2 = *(const float2*)(cb + (size_t)code * DIM + l * 2);
    const float o0 = xv.x + (c2.x - xv.x);
    const float o1 = xv.y + (c2.y - xv.y);
    *(float2*)(qout + (size_t)tok * DIM + l * 2) = make_float2(o0, o1);
    const float e0 = xv.x - c2.x, e1 = xv.y - c2.y;
    float msel = e0 * e0 + e1 * e1;
    float dt = xv.x * c2.x + xv.y * c2.y;
#pragma unroll
    for (int s = 32; s >= 1; s >>= 1) {
      msel += __shfl_xor(msel, s, 64);
      dt += __shfl_xor(dt, s, 64);
    }
    if (l == 0) {
      const float nx = fmaxf(sqrtf(sx), 1e-12f);
      const float nc = fmaxf(sqrtf(sumc2[code]), 1e-12f);
      msum[tok] = msel;
      csum[tok] = dt / (nx * nc);
      idx_out[tok] = (float)code;
      atomicAdd(&cnt[code], 1);
    }
  }
}

// Final reduction at 1024 threads.
__global__ __launch_bounds__(1024) void k_final(const int* __restrict__ cnt,
                                                const float* __restrict__ msum,
                                                const float* __restrict__ csum,
                                                const float* __restrict__ pairsum,
                                                const float* __restrict__ pairmin,
                                                float* __restrict__ outs) {
  __shared__ float sh[1024], sh2[1024], sh3[1024], sh4[1024];
  const int t = threadIdx.x;
  float ent = 0.0f;
  for (int k = t; k < KCB; k += 1024) {
    const float p = (float)cnt[k] * (1.0f / (float)NTOK);
    ent += p * logf(p + 1e-10f);
  }
  float ms = 0.0f, cs = 0.0f;
  for (int i = t; i < NTOK; i += 1024) { ms += msum[i]; cs += csum[i]; }
  float ps = 0.0f, pm = INFINITY;
  for (int i = t; i < 4096; i += 1024) { ps += pairsum[i]; pm = fminf(pm, pairmin[i]); }

  sh[t] = ent; sh2[t] = ms; sh3[t] = cs; sh4[t] = ps;
  __syncthreads();
  for (int s = 512; s >= 1; s >>= 1) {
    if (t < s) { sh[t] += sh[t + s]; sh2[t] += sh2[t + s];
                 sh3[t] += sh3[t + s]; sh4[t] += sh4[t + s]; }
    __syncthreads();
  }
  const float ent_tot = sh[0];
  const float ms_tot  = sh2[0];
  const float cs_tot  = sh3[0];
  const float ps_tot  = sh4[0];
  __syncthreads();
  sh[t] = pm;
  __syncthreads();
  for (int s = 512; s >= 1; s >>= 1) {
    if (t < s) sh[t] = fminf(sh[t], sh[t + s]);
    __syncthreads();
  }
  if (t == 0) {
    const float mse = ms_tot * (1.0f / (float)(NTOK * DIM));
    outs[0] = 0.25f * mse;
    outs[1] = mse;
    outs[2] = expf(-ent_tot);
    outs[3] = cs_tot * (1.0f / (float)NTOK);
    outs[4] = ps_tot / ((float)KCB * (float)(KCB - 1));
    outs[5] = sh[0];
  }
}

extern "C" void kernel_launch(void* const* d_in, const int* in_sizes, int n_in,
                              void* d_out, int out_size, void* d_ws, size_t ws_size,
                              hipStream_t stream) {
  const float* lat = (const float*)d_in[0];
  const float* cb  = (const float*)d_in[1];

  float* out     = (float*)d_out;
  float* qout    = out;
  float* idx_out = out + (size_t)NTOK * DIM;
  float* outs    = idx_out + NTOK;

  float* W        = (float*)d_ws;
  float* sumx2    = W;                             // NTOK
  float* sumc2    = sumx2 + NTOK;                  // KCB
  float* absum    = sumc2 + KCB;                   // NTOK
  int*   cnt      = (int*)(absum + NTOK);          // KCB
  float* msum     = (float*)(cnt + KCB);           // NTOK
  float* csum     = msum + NTOK;                   // NTOK
  float* pairsum  = csum + NTOK;                   // 4096
  float* pairmin  = pairsum + 4096;                // 4096
  unsigned short* cbh   = (unsigned short*)(pairmin + 4096);   // KCB*DIM
  unsigned short* gmax8 = cbh + (size_t)KCB * DIM;             // NTOK*NG8

  hipLaunchKernelGGL(k_prep, dim3((NTOK + KCB) / 4 + KCB * DIM / (256 * 8)),
                     dim3(256), 0, stream, lat, cb, sumx2, sumc2, absum, cnt, cbh);
  hipLaunchKernelGGL(k_approx, dim3(NTOK / 256, 32), dim3(256), 0, stream,
                     lat, cbh, gmax8);
  hipLaunchKernelGGL(k_resolve_pair, dim3(1024 + NTOK / 4), dim3(256), 0, stream,
                     lat, cb, sumx2, sumc2, absum, gmax8, cbh,
                     qout, idx_out, msum, csum, cnt, pairsum, pairmin);
  hipLaunchKernelGGL(k_final, dim3(1), dim3(1024), 0, stream, cnt,
                     msum, csum, pairsum, pairmin, outs);
}

// Round 22
// 115.237 us; speedup vs baseline: 4.6529x; 1.0733x over previous
//
#include <hip/hip_runtime.h>
#include <hip/hip_fp16.h>
#include <math.h>

#define NTOK 16384
#define KCB  4096
#define DIM  128
#define NG8  (KCB / 8)      // 512 8-code groups

typedef short bf16x8 __attribute__((ext_vector_type(8)));
typedef float f32x4  __attribute__((ext_vector_type(4)));

// RNE float -> bf16 bits
static __device__ inline unsigned short rne_bf16(float f) {
  unsigned u = __float_as_uint(f);
  return (unsigned short)((u + 0x7FFFu + ((u >> 16) & 1u)) >> 16);
}

// ---------------------------------------------------------------------------
// ws layout (float offsets from W):
//   [0]          sumx2[NTOK]
//   +NTOK        sumc2[KCB]
//   +KCB         absum[NTOK]
//   +NTOK        cnt[KCB] (int)
//   +KCB         msum[NTOK]
//   +NTOK        csum[NTOK]
//   +NTOK        pairsum[4096]
//   +4096        pairmin[4096]
//   +4096        cbh[KCB*DIM] (ushort bf16 hi)
//   +KCB*DIM/2   gmax8[NTOK*NG8] (ushort fp16, row-major per token)
// ---------------------------------------------------------------------------

// Fused: rownorm (+cnt zero) blocks [0, 5120) ; convert blocks [5120, 5376).
__global__ __launch_bounds__(256) void k_prep(const float* __restrict__ lat,
                                              const float* __restrict__ cb,
                                              float* __restrict__ sumx2,
                                              float* __restrict__ sumc2,
                                              float* __restrict__ absum,
                                              int* __restrict__ cnt,
                                              unsigned short* __restrict__ cbh) {
  if (blockIdx.x < (NTOK + KCB) / 4) {
    if (blockIdx.x < 16) cnt[blockIdx.x * 256 + threadIdx.x] = 0;
    const int row  = blockIdx.x * 4 + (threadIdx.x >> 6);
    const int lane = threadIdx.x & 63;
    const float* src = (row < NTOK) ? (lat + (size_t)row * DIM)
                                    : (cb + (size_t)(row - NTOK) * DIM);
    float2 v = *(const float2*)(src + lane * 2);
    double s  = (double)v.x * (double)v.x + (double)v.y * (double)v.y;
    double sa = fabs((double)v.x) + fabs((double)v.y);
#pragma unroll
    for (int m = 32; m >= 1; m >>= 1) {
      s  += __shfl_xor(s, m, 64);
      sa += __shfl_xor(sa, m, 64);
    }
    if (lane == 0) {
      if (row < NTOK) { sumx2[row] = (float)s; absum[row] = (float)sa; }
      else            sumc2[row - NTOK] = (float)s;
    }
  } else {
    const int b = blockIdx.x - (NTOK + KCB) / 4;
    const int base = (b * 256 + threadIdx.x) * 8;
    float4 v0 = *(const float4*)(cb + base);
    float4 v1 = *(const float4*)(cb + base + 4);
    ushort4 o0, o1;
    o0.x = rne_bf16(v0.x); o0.y = rne_bf16(v0.y); o0.z = rne_bf16(v0.z); o0.w = rne_bf16(v0.w);
    o1.x = rne_bf16(v1.x); o1.y = rne_bf16(v1.y); o1.z = rne_bf16(v1.z); o1.w = rne_bf16(v1.w);
    *(ushort4*)(cbh + base) = o0;
    *(ushort4*)(cbh + base + 4) = o1;
  }
}

// bf16 MFMA scan (R14/R16/R19 exact — gmax8 bit-identical).
__global__ __launch_bounds__(256) void k_approx(const float* __restrict__ lat,
                                                const unsigned short* __restrict__ cbh,
                                                unsigned short* __restrict__ gmax8) {
  __shared__ __align__(16) unsigned char smem[16384];
  __shared__ __align__(16) unsigned short gbuf[256][36];
  const int t = threadIdx.x;
  const int w = t >> 6, l = t & 63;
  const int l15 = l & 15, lq = l >> 4;
  const int tokb = blockIdx.x * 256 + w * 64;
  const int ct0 = blockIdx.y * 4;

  bf16x8 bfr[4][4];
#pragma unroll
  for (int ctile = 0; ctile < 4; ++ctile) {
    const float* row = lat + (size_t)(tokb + ctile * 16 + l15) * DIM;
#pragma unroll
    for (int ks = 0; ks < 4; ++ks) {
      const int d0 = ks * 32 + lq * 4;
      float4 c0 = *(const float4*)(row + d0);
      float4 c1 = *(const float4*)(row + d0 + 16);
      union { ushort4 u4[2]; bf16x8 v; } cv;
      cv.u4[0].x = rne_bf16(c0.x); cv.u4[0].y = rne_bf16(c0.y);
      cv.u4[0].z = rne_bf16(c0.z); cv.u4[0].w = rne_bf16(c0.w);
      cv.u4[1].x = rne_bf16(c1.x); cv.u4[1].y = rne_bf16(c1.y);
      cv.u4[1].z = rne_bf16(c1.z); cv.u4[1].w = rne_bf16(c1.w);
      bfr[ctile][ks] = cv.v;
    }
  }

  for (int it = 0; it < 4; ++it) {
    const int ct = ct0 + it;
    __syncthreads();
    {
      const int r = t & 63, seg = t >> 6;
      const unsigned short* src = cbh + (size_t)(ct * 64 + r) * DIM + seg * 32;
      const int sw = (r & 7) << 4;
#pragma unroll
      for (int i = 0; i < 4; ++i) {
        uint4 v = *(const uint4*)(src + i * 8);
        *(uint4*)(smem + r * 256 + ((seg * 64 + i * 16) ^ sw)) = v;
      }
    }
    __syncthreads();

#pragma unroll
    for (int rt = 0; rt < 4; ++rt) {
      const int row = rt * 16 + l15;
      const int sw = (row & 7) << 4;
      bf16x8 afr[4];
#pragma unroll
      for (int ks = 0; ks < 4; ++ks) {
        const int off = ks * 64 + lq * 8;
        union { uint2 u2[2]; bf16x8 v; } cv;
        cv.u2[0] = *(const uint2*)(smem + row * 256 + (off ^ sw));
        cv.u2[1] = *(const uint2*)(smem + row * 256 + (((off + 32)) ^ sw));
        afr[ks] = cv.v;
      }
      f32x4 acc[4];
#pragma unroll
      for (int c = 0; c < 4; ++c) acc[c] = (f32x4){0.0f, 0.0f, 0.0f, 0.0f};
#pragma unroll
      for (int ks = 0; ks < 4; ++ks)
#pragma unroll
        for (int c = 0; c < 4; ++c)
          acc[c] = __builtin_amdgcn_mfma_f32_16x16x32_bf16(afr[ks], bfr[c][ks], acc[c], 0, 0, 0);
#pragma unroll
      for (int c = 0; c < 4; ++c) {
        float gm = fmaxf(fmaxf(acc[c][0], acc[c][1]), fmaxf(acc[c][2], acc[c][3]));
        gm = fmaxf(gm, __shfl_xor(gm, 16, 64));
        if ((lq & 1) == 0) {
          const int tokl = w * 64 + c * 16 + l15;
          gbuf[tokl][it * 8 + rt * 2 + (lq >> 1)] =
              __half_as_ushort(__float2half(gm));
        }
      }
    }
  }

  __syncthreads();
  for (int c = t; c < 1024; c += 256) {
    const int token = c >> 2, seg = c & 3;
    uint2 a = *(const uint2*)(&gbuf[token][seg * 8]);
    uint2 b = *(const uint2*)(&gbuf[token][seg * 8 + 4]);
    uint4 o = make_uint4(a.x, a.y, b.x, b.y);
    *(uint4*)(gmax8 + (size_t)(blockIdx.x * 256 + token) * NG8 +
              blockIdx.y * 32 + seg * 8) = o;
  }
}

// Fused PAIR [0,1024) + RESOLVE [1024,5120) — R19 exact (tightened window).
__global__ __launch_bounds__(256) void k_resolve_pair(
    const float* __restrict__ lat,
    const float* __restrict__ cb,
    const float* __restrict__ sumx2,
    const float* __restrict__ sumc2,
    const float* __restrict__ absum,
    const unsigned short* __restrict__ gmax8,
    const unsigned short* __restrict__ cbh,
    float* __restrict__ qout,
    float* __restrict__ idx_out,
    float* __restrict__ msum,
    float* __restrict__ csum,
    int* __restrict__ cnt,
    float* __restrict__ pairsum,
    float* __restrict__ pairmin) {
  __shared__ __align__(16) unsigned char pool[16640];

  if (blockIdx.x < 1024) {
    // ---------------- PAIR path ----------------
    const int f = blockIdx.x;
    const int bx = f & 15, by = f >> 4;
    unsigned char* smem = pool;
    float* qs = (float*)(pool + 16384);
    const int t = threadIdx.x;
    const int w = t >> 6, l = t & 63;
    const int l15 = l & 15, lq = l >> 4;
    const int jb = bx * 256 + w * 64;
    const int kb = by * 64;

    {
      const int r = t & 63, seg = t >> 6;
      const unsigned short* src = cbh + (size_t)(kb + r) * DIM + seg * 32;
      const int sw = (r & 7) << 4;
#pragma unroll
      for (int i = 0; i < 4; ++i) {
        uint4 v = *(const uint4*)(src + i * 8);
        *(uint4*)(smem + r * 256 + ((seg * 64 + i * 16) ^ sw)) = v;
      }
      if (t < 64) qs[t] = sumc2[kb + t];
    }

    bf16x8 bfr[4][4];
    float qj[4];
#pragma unroll
    for (int ct = 0; ct < 4; ++ct) {
      const unsigned short* rh = cbh + (size_t)(jb + ct * 16 + l15) * DIM;
#pragma unroll
      for (int ks = 0; ks < 4; ++ks) {
        const int d0 = ks * 32 + lq * 4;
        union { ushort4 u4[2]; bf16x8 v; } cvv;
        cvv.u4[0] = *(const ushort4*)(rh + d0);
        cvv.u4[1] = *(const ushort4*)(rh + d0 + 16);
        bfr[ct][ks] = cvv.v;
      }
      qj[ct] = sumc2[jb + ct * 16 + l15];
    }
    __syncthreads();

    float lsum = 0.0f, lmin = INFINITY;

#pragma unroll
    for (int rt = 0; rt < 4; ++rt) {
      const int row = rt * 16 + l15;
      const int sw = (row & 7) << 4;
      bf16x8 afr[4];
#pragma unroll
      for (int ks = 0; ks < 4; ++ks) {
        const int off = ks * 64 + lq * 8;
        union { uint2 u2[2]; bf16x8 v; } cv;
        cv.u2[0] = *(const uint2*)(smem + row * 256 + (off ^ sw));
        cv.u2[1] = *(const uint2*)(smem + row * 256 + (((off + 32)) ^ sw));
        afr[ks] = cv.v;
      }
      f32x4 acc[4];
#pragma unroll
      for (int c = 0; c < 4; ++c) acc[c] = (f32x4){0.0f, 0.0f, 0.0f, 0.0f};
#pragma unroll
      for (int ks = 0; ks < 4; ++ks)
#pragma unroll
        for (int c = 0; c < 4; ++c)
          acc[c] = __builtin_amdgcn_mfma_f32_16x16x32_bf16(afr[ks], bfr[c][ks], acc[c], 0, 0, 0);

#pragma unroll
      for (int c = 0; c < 4; ++c) {
        const int jg = jb + c * 16 + l15;
#pragma unroll
        for (int reg = 0; reg < 4; ++reg) {
          const int krl = rt * 16 + lq * 4 + reg;
          const int kg = kb + krl;
          const float d2 = (qj[c] + qs[krl]) - 2.0f * acc[c][reg];
          const float dd = sqrtf(fmaxf(d2, 0.0f));
          lsum += dd;
          if (jg != kg) lmin = fminf(lmin, dd);
        }
      }
    }

#pragma unroll
    for (int s = 32; s >= 1; s >>= 1) {
      lsum += __shfl_xor(lsum, s, 64);
      lmin = fminf(lmin, __shfl_xor(lmin, s, 64));
    }
    if (l == 0) {
      const int slot = f * 4 + w;
      pairsum[slot] = lsum;
      pairmin[slot] = lmin;
    }
  } else {
    // ---------------- RESOLVE path ----------------
    const int bid = blockIdx.x - 1024;
    float (*xs)[DIM] = (float (*)[DIM])pool;
    unsigned short (*q)[NG8] = (unsigned short (*)[NG8])(pool + 2048);
    const int w = threadIdx.x >> 6, l = threadIdx.x & 63;
    const int tok = bid * 4 + w;

    const float2 xv = *(const float2*)(lat + (size_t)tok * DIM + l * 2);
    const uint4 hv = *(const uint4*)(gmax8 + (size_t)tok * NG8 + l * 8);
    const float sx = sumx2[tok];
    const float ab = absum[tok];
    *(float2*)(&xs[w][l * 2]) = xv;

    float hf[8];
    hf[0] = __half2float(__ushort_as_half((unsigned short)(hv.x & 0xFFFFu)));
    hf[1] = __half2float(__ushort_as_half((unsigned short)(hv.x >> 16)));
    hf[2] = __half2float(__ushort_as_half((unsigned short)(hv.y & 0xFFFFu)));
    hf[3] = __half2float(__ushort_as_half((unsigned short)(hv.y >> 16)));
    hf[4] = __half2float(__ushort_as_half((unsigned short)(hv.z & 0xFFFFu)));
    hf[5] = __half2float(__ushort_as_half((unsigned short)(hv.z >> 16)));
    hf[6] = __half2float(__ushort_as_half((unsigned short)(hv.w & 0xFFFFu)));
    hf[7] = __half2float(__ushort_as_half((unsigned short)(hv.w >> 16)));
    float m = hf[0];
#pragma unroll
    for (int i = 1; i < 8; ++i) m = fmaxf(m, hf[i]);
#pragma unroll
    for (int s = 32; s >= 1; s >>= 1) m = fmaxf(m, __shfl_xor(m, s, 64));
    const float thr = m - (ab * 2.0e-6f + 7.0e-5f);

    const unsigned long long ltm = (1ull << l) - 1ull;
    int n = 0;
#pragma unroll
    for (int i = 0; i < 8; ++i) {
      const bool f2 = (hf[i] >= thr);
      const unsigned long long b = __ballot(f2);
      if (f2) q[w][n + __popcll(b & ltm)] = (unsigned short)(l * 8 + i);
      n += __popcll(b);
    }

    const int slot = l >> 3, cidx = l & 7;
    unsigned long long bestp = ~0ull;
    const float4* xr4 = (const float4*)xs[w];

    for (int base = 0; base < n; base += 8) {
      unsigned long long pack = ~0ull;
      const int qi = base + slot;
      if (qi < n) {
        const int g = (int)q[w][qi];
        const int code = g * 8 + cidx;
        const float4* crow = (const float4*)(cb + (size_t)code * DIM);
        float acc = 0.0f;
#pragma unroll 8
        for (int ch = 0; ch < 32; ++ch) {
          const float4 c = crow[ch];
          const float4 x = xr4[ch];
          acc = fmaf(x.x, c.x, acc); acc = fmaf(x.y, c.y, acc);
          acc = fmaf(x.z, c.z, acc); acc = fmaf(x.w, c.w, acc);
        }
        const float dist = (sx - 2.0f * acc) + sumc2[code];
        pack = ((unsigned long long)__float_as_uint(dist) << 32) | (unsigned)code;
      }
#pragma unroll
      for (int s = 32; s >= 1; s >>= 1) {
        const unsigned long long o = __shfl_xor(pack, s, 64);
        pack = (o < pack) ? o : pack;
      }
      bestp = (pack < bestp) ? pack : bestp;
    }

    const int code = (int)(bestp & 0xFFFFFFFFull);
    const float2 c2 = *(const float2*)(cb + (size_t)code * DIM + l * 2);
    const float o0 = xv.x + (c2.x - xv.x);
    const float o1 = xv.y + (c2.y - xv.y);
    *(float2*)(qout + (size_t)tok * DIM + l * 2) = make_float2(o0, o1);
    const float e0 = xv.x - c2.x, e1 = xv.y - c2.y;
    float msel = e0 * e0 + e1 * e1;
    float dt = xv.x * c2.x + xv.y * c2.y;
#pragma unroll
    for (int s = 32; s >= 1; s >>= 1) {
      msel += __shfl_xor(msel, s, 64);
      dt += __shfl_xor(dt, s, 64);
    }
    if (l == 0) {
      const float nx = fmaxf(sqrtf(sx), 1e-12f);
      const float nc = fmaxf(sqrtf(sumc2[code]), 1e-12f);
      msum[tok] = msel;
      csum[tok] = dt / (nx * nc);
      idx_out[tok] = (float)code;
      atomicAdd(&cnt[code], 1);
    }
  }
}

// Final reduction at 1024 threads.
__global__ __launch_bounds__(1024) void k_final(const int* __restrict__ cnt,
                                                const float* __restrict__ msum,
                                                const float* __restrict__ csum,
                                                const float* __restrict__ pairsum,
                                                const float* __restrict__ pairmin,
                                                float* __restrict__ outs) {
  __shared__ float sh[1024], sh2[1024], sh3[1024], sh4[1024];
  const int t = threadIdx.x;
  float ent = 0.0f;
  for (int k = t; k < KCB; k += 1024) {
    const float p = (float)cnt[k] * (1.0f / (float)NTOK);
    ent += p * logf(p + 1e-10f);
  }
  float ms = 0.0f, cs = 0.0f;
  for (int i = t; i < NTOK; i += 1024) { ms += msum[i]; cs += csum[i]; }
  float ps = 0.0f, pm = INFINITY;
  for (int i = t; i < 4096; i += 1024) { ps += pairsum[i]; pm = fminf(pm, pairmin[i]); }

  sh[t] = ent; sh2[t] = ms; sh3[t] = cs; sh4[t] = ps;
  __syncthreads();
  for (int s = 512; s >= 1; s >>= 1) {
    if (t < s) { sh[t] += sh[t + s]; sh2[t] += sh2[t + s];
                 sh3[t] += sh3[t + s]; sh4[t] += sh4[t + s]; }
    __syncthreads();
  }
  const float ent_tot = sh[0];
  const float ms_tot  = sh2[0];
  const float cs_tot  = sh3[0];
  const float ps_tot  = sh4[0];
  __syncthreads();
  sh[t] = pm;
  __syncthreads();
  for (int s = 512; s >= 1; s >>= 1) {
    if (t < s) sh[t] = fminf(sh[t], sh[t + s]);
    __syncthreads();
  }
  if (t == 0) {
    const float mse = ms_tot * (1.0f / (float)(NTOK * DIM));
    outs[0] = 0.25f * mse;
    outs[1] = mse;
    outs[2] = expf(-ent_tot);
    outs[3] = cs_tot * (1.0f / (float)NTOK);
    outs[4] = ps_tot / ((float)KCB * (float)(KCB - 1));
    outs[5] = sh[0];
  }
}

extern "C" void kernel_launch(void* const* d_in, const int* in_sizes, int n_in,
                              void* d_out, int out_size, void* d_ws, size_t ws_size,
                              hipStream_t stream) {
  const float* lat = (const float*)d_in[0];
  const float* cb  = (const float*)d_in[1];

  float* out     = (float*)d_out;
  float* qout    = out;
  float* idx_out = out + (size_t)NTOK * DIM;
  float* outs    = idx_out + NTOK;

  float* W        = (float*)d_ws;
  float* sumx2    = W;                             // NTOK
  float* sumc2    = sumx2 + NTOK;                  // KCB
  float* absum    = sumc2 + KCB;                   // NTOK
  int*   cnt      = (int*)(absum + NTOK);          // KCB
  float* msum     = (float*)(cnt + KCB);           // NTOK
  float* csum     = msum + NTOK;                   // NTOK
  float* pairsum  = csum + NTOK;                   // 4096
  float* pairmin  = pairsum + 4096;                // 4096
  unsigned short* cbh   = (unsigned short*)(pairmin + 4096);   // KCB*DIM
  unsigned short* gmax8 = cbh + (size_t)KCB * DIM;             // NTOK*NG8

  hipLaunchKernelGGL(k_prep, dim3((NTOK + KCB) / 4 + KCB * DIM / (256 * 8)),
                     dim3(256), 0, stream, lat, cb, sumx2, sumc2, absum, cnt, cbh);
  hipLaunchKernelGGL(k_approx, dim3(NTOK / 256, 16), dim3(256), 0, stream,
                     lat, cbh, gmax8);
  hipLaunchKernelGGL(k_resolve_pair, dim3(1024 + NTOK / 4), dim3(256), 0, stream,
                     lat, cb, sumx2, sumc2, absum, gmax8, cbh,
                     qout, idx_out, msum, csum, cnt, pairsum, pairmin);
  hipLaunchKernelGGL(k_final, dim3(1), dim3(1024), 0, stream, cnt,
                     msum, csum, pairsum, pairmin, outs);
}